// Round 6
// baseline (101.936 us; speedup 1.0000x reference)
//
#include <hip/hip_runtime.h>
#include <hip/hip_bf16.h>
#include <stdint.h>

#define HSZ 2048
#define PRIME 500009u
#define CHUNK 128  // K-floats of hidden staged per iteration (512 B/row)
#define NCH 16     // 2048 / 128

typedef __attribute__((ext_vector_type(8))) short short8;
typedef __attribute__((ext_vector_type(4))) float f32x4;
typedef __attribute__((ext_vector_type(4))) unsigned uint4v;
typedef __attribute__((ext_vector_type(2))) unsigned uint2v;

#define MEMFENCE asm volatile("" ::: "memory")
#define BARRIER() do { MEMFENCE; __builtin_amdgcn_s_barrier(); MEMFENCE; } while (0)
#define WAIT_LGKM0 asm volatile("s_waitcnt lgkmcnt(0)" ::: "memory")
#define WAIT_VM(n) asm volatile("s_waitcnt vmcnt(" #n ")" ::: "memory")

__device__ __forceinline__ unsigned pk2(float x, float y) {
  __hip_bfloat162 h = __float22bfloat162_rn(make_float2(x, y));
  return *reinterpret_cast<unsigned*>(&h);
}
__device__ __forceinline__ short f2bf(float f) {
  __hip_bfloat16 h = __float2bfloat16(f);
  return *reinterpret_cast<short*>(&h);
}
__device__ __forceinline__ short8 pack8(float4 a, float4 b) {
  uint4v u = {pk2(a.x, a.y), pk2(a.z, a.w), pk2(b.x, b.y), pk2(b.z, b.w)};
  return __builtin_bit_cast(short8, u);
}
__device__ __forceinline__ short8 load8_bf(const float* __restrict__ p) {
  float4 a = *reinterpret_cast<const float4*>(p);
  float4 b = *reinterpret_cast<const float4*>(p + 4);
  return pack8(a, b);
}
// async global->LDS, 16B/lane, LDS dest = wave-uniform base + lane*16 (linear)
__device__ __forceinline__ void gload_lds16(const float* g, void* l) {
  __builtin_amdgcn_global_load_lds(
      (const __attribute__((address_space(1))) void*)g,
      (__attribute__((address_space(3))) void*)l, 16, 0, 0);
}

// ============ fused kernel: 1024 blocks x 256 threads, 16 tokens/block ============
// ~44 KB LDS -> 3 blocks/CU; grid 1024 > resident 768 -> generation pipelining:
// late blocks' HBM-light front-end overlaps early blocks' read/write streaming.
__global__ __launch_bounds__(256, 3) void engram_fused(
    const int* __restrict__ ids, const int* __restrict__ mapping,
    const unsigned* __restrict__ mult, const float* __restrict__ table,
    const float* __restrict__ Wh, const float* __restrict__ hidden,
    const float* __restrict__ cw, const float* __restrict__ cb,
    const float* __restrict__ Wg, const float* __restrict__ Wo,
    float* __restrict__ out) {
  __shared__ __align__(16) float hbuf[2][16][CHUNK];  // 16 KB hidden double buffer
  __shared__ __align__(16) short A_lds[32][264];      // gathered table rows (bf16)
  __shared__ __align__(16) float emb32[32][36];       // emb0, 32 slots (16 lookback)
  __shared__ float emb_c[16][33];                     // conv output
  __shared__ __align__(16) short ge_lds[16][40];      // gate*emb bf16
  __shared__ float accred[2][4][64];                  // K-half reduce
  __shared__ int idx_lds[256];                        // 32 slots x 8 heads

  const int tid = threadIdx.x;
  const int wid = tid >> 6, lane = tid & 63;
  const int l16 = lane & 15, q = lane >> 4;
  const int t0 = blockIdx.x * 16;

  // stage 16 x CHUNK f32 of hidden; 1 instr = 2 rows (512 B each); wave w: rows w*4..w*4+3.
  // LDS dest linear; global src col byte-XOR ((row&7)<<4); read side applies same XOR.
  auto STAGE = [&](int buf, int kc) {
#pragma unroll
    for (int j = 0; j < 2; ++j) {
      int r0 = wid * 4 + j * 2;
      int r = r0 + (lane >> 5);
      unsigned cf = (((unsigned)(lane & 31) * 16u) ^ (((unsigned)r & 7u) << 4)) >> 2;
      const float* src = hidden + (size_t)(t0 + r) * HSZ + kc * CHUNK + cf;
      gload_lds16(src, &hbuf[buf][r0][0]);
    }
  };

  STAGE(0, 0);
  STAGE(1, 1);  // chunks 0,1 fly under the whole front-end

  // ---- 1) hash: 32 slots x 8 heads, 1/thread; slot i = token t0-16+i (clamped) ----
  {
    int slot = tid >> 3, head = tid & 7;
    int tg = t0 - 16 + slot;
    if (tg < 0) tg = 0;
    int b = tg >> 12, s = tg & 4095;
    const int* idb = ids + (b << 12);
    int s1 = s + 1 > 4095 ? 4095 : s + 1;
    int s2 = s + 2 > 4095 ? 4095 : s + 2;
    uint64_t c0 = (unsigned)mapping[idb[s]];
    uint64_t c1 = (unsigned)mapping[idb[s1]];
    uint64_t c2 = (unsigned)mapping[idb[s2]];
    int mb = head * 3;  // multipliers row-major [2][4][3]
    uint64_t h = (c0 * (uint64_t)mult[mb]) ^ (c1 * (uint64_t)mult[mb + 1]);
    if (head >= 4) h ^= c2 * (uint64_t)mult[mb + 2];
    idx_lds[tid] = (int)((unsigned)(h % PRIME) + (unsigned)head * PRIME);
  }
  WAIT_LGKM0; BARRIER();

  // ---- 2) gather 256 table rows (128 B each, 8 lanes/row) -> A_lds bf16 ----
#pragma unroll
  for (int p = 0; p < 8; ++p) {
    int r = p * 32 + (tid >> 3);
    int c4 = (tid & 7) * 4;
    int row = idx_lds[r];
    float4 v = *reinterpret_cast<const float4*>(table + (size_t)row * 32 + c4);
    uint2v pk = {pk2(v.x, v.y), pk2(v.z, v.w)};
    *reinterpret_cast<uint2v*>(&A_lds[r >> 3][(r & 7) * 32 + c4]) = pk;
  }
  WAIT_LGKM0; BARRIER();

  // ---- 3) emb0 MFMA: 4 jobs (2 slot-tiles x 2 e-tiles), one per wave ----
  {
    int jt = wid >> 1, e0 = (wid & 1) * 16;
    f32x4 acc = {0.f, 0.f, 0.f, 0.f};
#pragma unroll
    for (int ks = 0; ks < 8; ++ks) {
      short8 wf = load8_bf(Wh + (size_t)(e0 + l16) * 256 + ks * 32 + q * 8);
      short8 a = *reinterpret_cast<const short8*>(&A_lds[jt * 16 + l16][ks * 32 + q * 8]);
      acc = __builtin_amdgcn_mfma_f32_16x16x32_bf16(wf, a, acc, 0, 0, 0);
    }
    // D: col=slot(l16), row=e(q*4+j) -> 16B store
    *reinterpret_cast<f32x4*>(&emb32[jt * 16 + l16][e0 + q * 4]) = acc;
  }
  WAIT_LGKM0; BARRIER();

  // ---- 4) conv: emb_c[tl][e] = cb + sum_j cw[e,j]*emb32[13+tl+j][e] (batch zero-pad) ----
#pragma unroll
  for (int it = 0; it < 2; ++it) {
    int ii = it * 256 + tid;
    int tl = ii >> 5, e = ii & 31;
    int s = (t0 & 4095) + tl;
    float a = cb[e];
#pragma unroll
    for (int j = 0; j < 4; ++j)
      if (s - 3 + j >= 0) a += cw[e * 4 + j] * emb32[13 + tl + j][e];
    emb_c[tl][e] = a;
  }
  WAIT_LGKM0; BARRIER();

  // ---- 5) gate MLP: wave (ee,kh) = e-tile x K-half of each chunk; counted vmcnt ----
  const int ee = wid & 1, kh = wid >> 1;
  const unsigned sw = ((unsigned)l16 & 7u) << 4;
  const char* hb0 = (const char*)&hbuf[0][0][0] + l16 * 512;
  const char* hb1 = (const char*)&hbuf[1][0][0] + l16 * 512;
  const float* wgp = Wg + (size_t)(ee * 16 + l16) * HSZ + kh * 64 + q * 8;
  const unsigned x0 = (unsigned)(kh * 256 + q * 32);
  f32x4 acc = {0.f, 0.f, 0.f, 0.f};

  for (int kc = 0; kc < NCH - 1; ++kc) {
    WAIT_VM(8);
    BARRIER();  // chunk kc readable by all waves
    const char* hb = (kc & 1) ? hb1 : hb0;
    float4 a0 = *reinterpret_cast<const float4*>(hb + (x0 ^ sw));
    float4 a1 = *reinterpret_cast<const float4*>(hb + ((x0 + 16) ^ sw));
    float4 a2 = *reinterpret_cast<const float4*>(hb + ((x0 + 128) ^ sw));
    float4 a3 = *reinterpret_cast<const float4*>(hb + ((x0 + 144) ^ sw));
    short8 A0 = pack8(a0, a1);
    short8 A1 = pack8(a2, a3);
    short8 B0 = load8_bf(wgp + kc * CHUNK);       // pack waits B -> forces older stages done
    short8 B1 = load8_bf(wgp + kc * CHUNK + 32);
    WAIT_LGKM0;  // our ds_reads of chunk kc are in regs
    BARRIER();   // all waves done with buf[kc&1]
    if (kc < NCH - 2) STAGE(kc & 1, kc + 2);      // prefetch flies across barriers
    acc = __builtin_amdgcn_mfma_f32_16x16x32_bf16(A0, B0, acc, 0, 0, 0);
    acc = __builtin_amdgcn_mfma_f32_16x16x32_bf16(A1, B1, acc, 0, 0, 0);
  }
  {  // final chunk (odd -> hb1), full drain
    WAIT_VM(0);
    BARRIER();
    float4 a0 = *reinterpret_cast<const float4*>(hb1 + (x0 ^ sw));
    float4 a1 = *reinterpret_cast<const float4*>(hb1 + ((x0 + 16) ^ sw));
    float4 a2 = *reinterpret_cast<const float4*>(hb1 + ((x0 + 128) ^ sw));
    float4 a3 = *reinterpret_cast<const float4*>(hb1 + ((x0 + 144) ^ sw));
    short8 B0 = load8_bf(wgp + (NCH - 1) * CHUNK);
    short8 B1 = load8_bf(wgp + (NCH - 1) * CHUNK + 32);
    acc = __builtin_amdgcn_mfma_f32_16x16x32_bf16(pack8(a0, a1), B0, acc, 0, 0, 0);
    acc = __builtin_amdgcn_mfma_f32_16x16x32_bf16(pack8(a2, a3), B1, acc, 0, 0, 0);
  }

  // ---- 6) K-half reduce + sigmoid*emb -> ge_lds ----
  if (kh == 1) {
#pragma unroll
    for (int j = 0; j < 4; ++j) accred[ee][j][lane] = acc[j];
  }
  WAIT_LGKM0; BARRIER();
  if (kh == 0) {
#pragma unroll
    for (int j = 0; j < 4; ++j) {
      float s = acc[j] + accred[ee][j][lane];
      int r = q * 4 + j, c = ee * 16 + l16;  // D: col=gate-e(l16), row=token(q*4+j)
      float g = 1.f / (1.f + __expf(-s));
      ge_lds[r][c] = f2bf(g * emb_c[r][c]);
    }
  }
  WAIT_LGKM0; BARRIER();

  // ---- 7) out[t,h] = ge @ Wo.T (swapped -> float4 stores); 512 h-cols/wave ----
  short8 Af = *reinterpret_cast<const short8*>(&ge_lds[l16][q * 8]);
  float* orow = out + (size_t)(t0 + l16) * HSZ;
#pragma unroll 4
  for (int ht = 0; ht < 32; ++ht) {
    int h0 = wid * 512 + ht * 16;
    short8 aw = load8_bf(Wo + (size_t)(h0 + l16) * 32 + q * 8);
    f32x4 z = {0.f, 0.f, 0.f, 0.f};
    f32x4 o = __builtin_amdgcn_mfma_f32_16x16x32_bf16(aw, Af, z, 0, 0, 0);
    *reinterpret_cast<f32x4*>(orow + h0 + q * 4) = o;  // D: col=token(l16), row=h(q*4+j)
  }
}

extern "C" void kernel_launch(void* const* d_in, const int* in_sizes, int n_in,
                              void* d_out, int out_size, void* d_ws, size_t ws_size,
                              hipStream_t stream) {
  const int* ids = (const int*)d_in[0];
  const float* hidden = (const float*)d_in[1];
  const int* mapping = (const int*)d_in[2];
  const unsigned* mult = (const unsigned*)d_in[3];  // delivered as int32; low bits exact
  const float* table = (const float*)d_in[4];
  const float* cw = (const float*)d_in[5];
  const float* cb = (const float*)d_in[6];
  const float* Wh = (const float*)d_in[7];
  const float* Wg = (const float*)d_in[8];
  const float* Wo = (const float*)d_in[9];
  float* out = (float*)d_out;

  engram_fused<<<1024, 256, 0, stream>>>(ids, mapping, mult, table, Wh, hidden,
                                         cw, cb, Wg, Wo, out);
}

// Round 7
// 92.554 us; speedup vs baseline: 1.1014x; 1.1014x over previous
//
#include <hip/hip_runtime.h>
#include <hip/hip_bf16.h>
#include <stdint.h>

#define HSZ 2048
#define PRIME 500009u
#define CHUNK 128  // K-floats of hidden staged per iteration (512 B/row)
#define NCH 16     // 2048 / 128

typedef __attribute__((ext_vector_type(8))) short short8;
typedef __attribute__((ext_vector_type(4))) float f32x4;
typedef __attribute__((ext_vector_type(4))) unsigned uint4v;
typedef __attribute__((ext_vector_type(2))) unsigned uint2v;

#define MEMFENCE asm volatile("" ::: "memory")
#define BARRIER() do { MEMFENCE; __builtin_amdgcn_s_barrier(); MEMFENCE; } while (0)
#define WAIT_LGKM0 asm volatile("s_waitcnt lgkmcnt(0)" ::: "memory")
#define WAIT_VM(n) asm volatile("s_waitcnt vmcnt(" #n ")" ::: "memory")

__device__ __forceinline__ unsigned pk2(float x, float y) {
  __hip_bfloat162 h = __float22bfloat162_rn(make_float2(x, y));
  return *reinterpret_cast<unsigned*>(&h);
}
__device__ __forceinline__ short f2bf(float f) {
  __hip_bfloat16 h = __float2bfloat16(f);
  return *reinterpret_cast<short*>(&h);
}
__device__ __forceinline__ short8 pack8(float4 a, float4 b) {
  uint4v u = {pk2(a.x, a.y), pk2(a.z, a.w), pk2(b.x, b.y), pk2(b.z, b.w)};
  return __builtin_bit_cast(short8, u);
}
__device__ __forceinline__ short8 load8_bf(const float* __restrict__ p) {
  float4 a = *reinterpret_cast<const float4*>(p);
  float4 b = *reinterpret_cast<const float4*>(p + 4);
  return pack8(a, b);
}
// async global->LDS, 16B/lane, LDS dest = wave-uniform base + lane*16 (linear)
__device__ __forceinline__ void gload_lds16(const float* g, void* l) {
  __builtin_amdgcn_global_load_lds(
      (const __attribute__((address_space(1))) void*)g,
      (__attribute__((address_space(3))) void*)l, 16, 0, 0);
}

// ============ fused kernel: 512 blocks x 256 threads, 32 tokens/block ============
// R5 structure (best known: 79 us) + CHUNK=128 (half the MLP barriers) +
// stage-after-hash + out-phase unroll-8.
__global__ __launch_bounds__(256, 2) void engram_fused(
    const int* __restrict__ ids, const int* __restrict__ mapping,
    const unsigned* __restrict__ mult, const float* __restrict__ table,
    const float* __restrict__ Wh, const float* __restrict__ hidden,
    const float* __restrict__ cw, const float* __restrict__ cb,
    const float* __restrict__ Wg, const float* __restrict__ Wo,
    float* __restrict__ out) {
  __shared__ __align__(16) float hbuf[2][32][CHUNK];  // 32 KB hidden double buffer
  __shared__ __align__(16) short A_lds[48][264];      // gathered table rows, bf16
  __shared__ __align__(16) float emb48[48][36];       // emb0 for 48 slots
  __shared__ float emb_c[32][33];                     // conv output
  __shared__ __align__(16) short ge_lds[32][40];      // gate*emb bf16
  __shared__ int idx_lds[384];                        // 48 slots x 8 heads

  const int tid = threadIdx.x;
  const int wid = tid >> 6, lane = tid & 63;
  const int l16 = lane & 15, q = lane >> 4;
  const int t0 = blockIdx.x * 32;

  // stage one 32 x CHUNK f32 chunk of hidden; 1 instr covers 2 rows (512 B each);
  // wave w stages rows w*8..w*8+7 (4 instrs). LDS dest linear; global src col
  // byte-XOR-swizzled by ((row&7)<<4); read side applies the same XOR.
  auto STAGE = [&](int buf, int kc) {
#pragma unroll
    for (int j = 0; j < 4; ++j) {
      int r0 = wid * 8 + j * 2;
      int r = r0 + (lane >> 5);
      unsigned cf = (((unsigned)(lane & 31) * 16u) ^ (((unsigned)r & 7u) << 4)) >> 2;
      const float* src = hidden + (size_t)(t0 + r) * HSZ + kc * CHUNK + cf;
      gload_lds16(src, &hbuf[buf][r0][0]);
    }
  };

  // ---- 1) hash: 48 slots x 8 heads; slot i = token t0-16+i (clamped; masked later) ----
#pragma unroll
  for (int p = 0; p < 2; ++p) {
    int hh = p * 256 + tid;
    if (hh < 384) {
      int slot = hh >> 3, head = hh & 7;
      int tg = t0 - 16 + slot;
      if (tg < 0) tg = 0;
      int b = tg >> 12, s = tg & 4095;
      const int* idb = ids + (b << 12);
      int s1 = s + 1 > 4095 ? 4095 : s + 1;
      int s2 = s + 2 > 4095 ? 4095 : s + 2;
      uint64_t c0 = (unsigned)mapping[idb[s]];
      uint64_t c1 = (unsigned)mapping[idb[s1]];
      uint64_t c2 = (unsigned)mapping[idb[s2]];
      int mb = head * 3;  // multipliers row-major [2][4][3]
      uint64_t h = (c0 * (uint64_t)mult[mb]) ^ (c1 * (uint64_t)mult[mb + 1]);
      if (head >= 4) h ^= c2 * (uint64_t)mult[mb + 2];
      idx_lds[hh] = (int)((unsigned)(h % PRIME) + (unsigned)head * PRIME);
    }
  }

  // chunks 0,1 fly under gather + emb0 + conv (issued after hash's dependent loads
  // so the ids->mapping chain isn't force-retired behind the stage burst)
  STAGE(0, 0);
  STAGE(1, 1);

  WAIT_LGKM0; BARRIER();

  // ---- 2) gather 384 table rows (128 B each, 8 lanes/row) -> A_lds bf16 ----
#pragma unroll
  for (int p = 0; p < 12; ++p) {
    int r = p * 32 + (tid >> 3);
    int c4 = (tid & 7) * 4;
    int row = idx_lds[r];
    float4 v = *reinterpret_cast<const float4*>(table + (size_t)row * 32 + c4);
    uint2v pk = {pk2(v.x, v.y), pk2(v.z, v.w)};
    *reinterpret_cast<uint2v*>(&A_lds[r >> 3][(r & 7) * 32 + c4]) = pk;
  }
  WAIT_LGKM0; BARRIER();

  // ---- 3) emb0 MFMA: 6 jobs (3 slot-tiles x 2 e-tiles), swapped operands ----
  for (int job = wid; job < 6; job += 4) {
    int jt = job >> 1, e0 = (job & 1) * 16;
    f32x4 acc = {0.f, 0.f, 0.f, 0.f};
#pragma unroll
    for (int ks = 0; ks < 8; ++ks) {
      short8 wf = load8_bf(Wh + (size_t)(e0 + l16) * 256 + ks * 32 + q * 8);
      short8 a = *reinterpret_cast<const short8*>(&A_lds[jt * 16 + l16][ks * 32 + q * 8]);
      acc = __builtin_amdgcn_mfma_f32_16x16x32_bf16(wf, a, acc, 0, 0, 0);
    }
    // D: col=slot(l16), row=e(q*4+j) -> 16B store
    *reinterpret_cast<f32x4*>(&emb48[jt * 16 + l16][e0 + q * 4]) = acc;
  }
  WAIT_LGKM0; BARRIER();

  // ---- 4) conv: emb_c[tl][e] = cb + sum_j cw[e,j]*emb48[13+tl+j][e] (batch zero-pad) ----
#pragma unroll
  for (int it = 0; it < 4; ++it) {
    int ii = it * 256 + tid;
    int tl = ii >> 5, e = ii & 31;
    int s = (t0 & 4095) + tl;
    float a = cb[e];
#pragma unroll
    for (int j = 0; j < 4; ++j)
      if (s - 3 + j >= 0) a += cw[e * 4 + j] * emb48[13 + tl + j][e];
    emb_c[tl][e] = a;
  }
  WAIT_LGKM0; BARRIER();

  // ---- 5) gate MLP: wave (tt,ee) owns 16x16 tile, full K; counted-vmcnt pipeline ----
  const int tt = wid >> 1, ee = wid & 1;
  const int R = tt * 16 + l16;
  const unsigned sw = ((unsigned)R & 7u) << 4;
  const char* hb0 = (const char*)&hbuf[0][R][0];
  const char* hb1 = (const char*)&hbuf[1][R][0];
  const float* wgp = Wg + (size_t)(ee * 16 + l16) * HSZ + q * 8;
  f32x4 acc = {0.f, 0.f, 0.f, 0.f};

  for (int kc = 0; kc < NCH - 1; ++kc) {
    WAIT_VM(12);
    BARRIER();  // chunk kc readable by all waves (stage(kc) retired via B(kc-1) in-order)
    const char* hb = (kc & 1) ? hb1 : hb0;
    short8 A[4], B[4];
#pragma unroll
    for (int ks = 0; ks < 4; ++ks) {
      unsigned x0 = (unsigned)(ks * 128 + q * 32);
      float4 a0 = *reinterpret_cast<const float4*>(hb + (x0 ^ sw));
      float4 a1 = *reinterpret_cast<const float4*>(hb + ((x0 + 16) ^ sw));
      A[ks] = pack8(a0, a1);
      B[ks] = load8_bf(wgp + kc * CHUNK + ks * 32);
    }
    WAIT_LGKM0;  // our ds_reads of chunk kc are in regs
    BARRIER();   // all waves done with buf[kc&1]
    if (kc < NCH - 2) STAGE(kc & 1, kc + 2);  // prefetch flies across barriers
#pragma unroll
    for (int ks = 0; ks < 4; ++ks)
      acc = __builtin_amdgcn_mfma_f32_16x16x32_bf16(A[ks], B[ks], acc, 0, 0, 0);
  }
  {  // final chunk (NCH-1, odd -> hb1), full drain
    WAIT_VM(0);
    BARRIER();
#pragma unroll
    for (int ks = 0; ks < 4; ++ks) {
      unsigned x0 = (unsigned)(ks * 128 + q * 32);
      float4 a0 = *reinterpret_cast<const float4*>(hb1 + (x0 ^ sw));
      float4 a1 = *reinterpret_cast<const float4*>(hb1 + ((x0 + 16) ^ sw));
      short8 B0 = load8_bf(wgp + (NCH - 1) * CHUNK + ks * 32);
      acc = __builtin_amdgcn_mfma_f32_16x16x32_bf16(pack8(a0, a1), B0, acc, 0, 0, 0);
    }
  }

  // ---- 6) sigmoid * conv-emb -> ge_lds (each wave writes its own 16x16 quadrant) ----
#pragma unroll
  for (int j = 0; j < 4; ++j) {
    int r = tt * 16 + q * 4 + j, c = ee * 16 + l16;
    float g = 1.f / (1.f + __expf(-acc[j]));
    ge_lds[r][c] = f2bf(g * emb_c[r][c]);
  }
  WAIT_LGKM0; BARRIER();

  // ---- 7) out[t,h] = ge @ Wo.T (swapped -> float4 stores); 512 h-cols/wave ----
  short8 Af0 = *reinterpret_cast<const short8*>(&ge_lds[l16][q * 8]);
  short8 Af1 = *reinterpret_cast<const short8*>(&ge_lds[16 + l16][q * 8]);
  float* orow0 = out + (size_t)(t0 + l16) * HSZ;
  float* orow1 = out + (size_t)(t0 + 16 + l16) * HSZ;
  int hbase = wid * 512;
#pragma unroll 8
  for (int ht = 0; ht < 32; ++ht) {
    int h0 = hbase + ht * 16;
    short8 aw = load8_bf(Wo + (size_t)(h0 + l16) * 32 + q * 8);
    f32x4 z = {0.f, 0.f, 0.f, 0.f};
    f32x4 o0 = __builtin_amdgcn_mfma_f32_16x16x32_bf16(aw, Af0, z, 0, 0, 0);
    f32x4 o1 = __builtin_amdgcn_mfma_f32_16x16x32_bf16(aw, Af1, z, 0, 0, 0);
    *reinterpret_cast<f32x4*>(orow0 + h0 + q * 4) = o0;
    *reinterpret_cast<f32x4*>(orow1 + h0 + q * 4) = o1;
  }
}

extern "C" void kernel_launch(void* const* d_in, const int* in_sizes, int n_in,
                              void* d_out, int out_size, void* d_ws, size_t ws_size,
                              hipStream_t stream) {
  const int* ids = (const int*)d_in[0];
  const float* hidden = (const float*)d_in[1];
  const int* mapping = (const int*)d_in[2];
  const unsigned* mult = (const unsigned*)d_in[3];  // delivered as int32; low bits exact
  const float* table = (const float*)d_in[4];
  const float* cw = (const float*)d_in[5];
  const float* cb = (const float*)d_in[6];
  const float* Wh = (const float*)d_in[7];
  const float* Wg = (const float*)d_in[8];
  const float* Wo = (const float*)d_in[9];
  float* out = (float*)d_out;

  engram_fused<<<512, 256, 0, stream>>>(ids, mapping, mult, table, Wh, hidden,
                                        cw, cb, Wg, Wo, out);
}

// Round 8
// 76.914 us; speedup vs baseline: 1.3253x; 1.2033x over previous
//
#include <hip/hip_runtime.h>
#include <hip/hip_bf16.h>
#include <stdint.h>

#define HSZ 2048
#define PRIME 500009u
#define CHUNK 64   // K-floats of hidden/Wg staged per iteration (256 B/row)
#define NCH 32     // 2048 / 64

typedef __attribute__((ext_vector_type(8))) short short8;
typedef __attribute__((ext_vector_type(4))) float f32x4;
typedef __attribute__((ext_vector_type(4))) unsigned uint4v;
typedef __attribute__((ext_vector_type(2))) unsigned uint2v;

#define MEMFENCE asm volatile("" ::: "memory")
#define BARRIER() do { MEMFENCE; __builtin_amdgcn_s_barrier(); MEMFENCE; } while (0)
#define WAIT_LGKM0 asm volatile("s_waitcnt lgkmcnt(0)" ::: "memory")
#define WAIT_VM(n) asm volatile("s_waitcnt vmcnt(" #n ")" ::: "memory")

__device__ __forceinline__ unsigned pk2(float x, float y) {
  __hip_bfloat162 h = __float22bfloat162_rn(make_float2(x, y));
  return *reinterpret_cast<unsigned*>(&h);
}
__device__ __forceinline__ short f2bf(float f) {
  __hip_bfloat16 h = __float2bfloat16(f);
  return *reinterpret_cast<short*>(&h);
}
__device__ __forceinline__ short8 pack8(float4 a, float4 b) {
  uint4v u = {pk2(a.x, a.y), pk2(a.z, a.w), pk2(b.x, b.y), pk2(b.z, b.w)};
  return __builtin_bit_cast(short8, u);
}
__device__ __forceinline__ short8 load8_bf(const float* __restrict__ p) {
  float4 a = *reinterpret_cast<const float4*>(p);
  float4 b = *reinterpret_cast<const float4*>(p + 4);
  return pack8(a, b);
}
// async global->LDS, 16B/lane, LDS dest = wave-uniform base + lane*16 (linear)
__device__ __forceinline__ void gload_lds16(const float* g, void* l) {
  __builtin_amdgcn_global_load_lds(
      (const __attribute__((address_space(1))) void*)g,
      (__attribute__((address_space(3))) void*)l, 16, 0, 0);
}

// ============ fused kernel: 512 blocks x 256 threads, 32 tokens/block ============
// R5 structure + ONE change: Wg K-chunks are ALSO staged via global_load_lds,
// making the MLP loop vmem-clean (no global->VGPR loads), so in-order vmcnt
// retirement never force-drains the STAGE pipeline (exact counted waits).
__global__ __launch_bounds__(256, 2) void engram_fused(
    const int* __restrict__ ids, const int* __restrict__ mapping,
    const unsigned* __restrict__ mult, const float* __restrict__ table,
    const float* __restrict__ Wh, const float* __restrict__ hidden,
    const float* __restrict__ cw, const float* __restrict__ cb,
    const float* __restrict__ Wg, const float* __restrict__ Wo,
    float* __restrict__ out) {
  __shared__ __align__(16) float hbuf[2][32][CHUNK];   // 16 KB hidden double buffer
  __shared__ __align__(16) float wgbuf[2][32][CHUNK];  // 16 KB Wg double buffer
  __shared__ __align__(16) short A_lds[48][264];       // gathered table rows, bf16
  __shared__ __align__(16) float emb48[48][36];        // emb0 for 48 slots
  __shared__ float emb_c[32][33];                      // conv output
  __shared__ __align__(16) short ge_lds[32][40];       // gate*emb bf16
  __shared__ int idx_lds[384];                         // 48 slots x 8 heads

  const int tid = threadIdx.x;
  const int wid = tid >> 6, lane = tid & 63;
  const int l16 = lane & 15, q = lane >> 4;
  const int t0 = blockIdx.x * 32;

  // stage one K-chunk: hidden rows t0..t0+31 and Wg rows 0..31, 256 B/row each.
  // 1 instr = 4 rows (64 lanes x 16 B). LDS dest linear; global src col
  // byte-XOR-swizzled by ((row&7)<<4); read side applies the same XOR.
  auto STAGE = [&](int buf, int kc) {
#pragma unroll
    for (int j = 0; j < 2; ++j) {
      int r0 = wid * 8 + j * 4;
      int r = r0 + (lane >> 4);
      unsigned c4 = (((unsigned)l16 * 16u) ^ (((unsigned)r & 7u) << 4)) >> 2;
      const float* src = hidden + (size_t)(t0 + r) * HSZ + kc * CHUNK + c4;
      gload_lds16(src, &hbuf[buf][r0][0]);
    }
#pragma unroll
    for (int j = 0; j < 2; ++j) {
      int r0 = wid * 8 + j * 4;
      int r = r0 + (lane >> 4);
      unsigned c4 = (((unsigned)l16 * 16u) ^ (((unsigned)r & 7u) << 4)) >> 2;
      const float* src = Wg + (size_t)r * HSZ + kc * CHUNK + c4;
      gload_lds16(src, &wgbuf[buf][r0][0]);
    }
  };

  STAGE(0, 0);
  STAGE(1, 1);  // chunks 0,1 fly under the whole front-end

  // ---- 1) hash: 48 slots x 8 heads; slot i = token t0-16+i (clamped; masked later) ----
#pragma unroll
  for (int p = 0; p < 2; ++p) {
    int hh = p * 256 + tid;
    if (hh < 384) {
      int slot = hh >> 3, head = hh & 7;
      int tg = t0 - 16 + slot;
      if (tg < 0) tg = 0;
      int b = tg >> 12, s = tg & 4095;
      const int* idb = ids + (b << 12);
      int s1 = s + 1 > 4095 ? 4095 : s + 1;
      int s2 = s + 2 > 4095 ? 4095 : s + 2;
      uint64_t c0 = (unsigned)mapping[idb[s]];
      uint64_t c1 = (unsigned)mapping[idb[s1]];
      uint64_t c2 = (unsigned)mapping[idb[s2]];
      int mb = head * 3;  // multipliers row-major [2][4][3]
      uint64_t h = (c0 * (uint64_t)mult[mb]) ^ (c1 * (uint64_t)mult[mb + 1]);
      if (head >= 4) h ^= c2 * (uint64_t)mult[mb + 2];
      idx_lds[hh] = (int)((unsigned)(h % PRIME) + (unsigned)head * PRIME);
    }
  }
  WAIT_LGKM0; BARRIER();

  // ---- 2) gather 384 table rows (128 B each, 8 lanes/row) -> A_lds bf16 ----
#pragma unroll
  for (int p = 0; p < 12; ++p) {
    int r = p * 32 + (tid >> 3);
    int c4 = (tid & 7) * 4;
    int row = idx_lds[r];
    float4 v = *reinterpret_cast<const float4*>(table + (size_t)row * 32 + c4);
    uint2v pk = {pk2(v.x, v.y), pk2(v.z, v.w)};
    *reinterpret_cast<uint2v*>(&A_lds[r >> 3][(r & 7) * 32 + c4]) = pk;
  }
  WAIT_LGKM0; BARRIER();

  // ---- 3) emb0 MFMA: 6 jobs (3 slot-tiles x 2 e-tiles), swapped operands ----
  for (int job = wid; job < 6; job += 4) {
    int jt = job >> 1, e0 = (job & 1) * 16;
    f32x4 acc = {0.f, 0.f, 0.f, 0.f};
#pragma unroll
    for (int ks = 0; ks < 8; ++ks) {
      short8 wf = load8_bf(Wh + (size_t)(e0 + l16) * 256 + ks * 32 + q * 8);
      short8 a = *reinterpret_cast<const short8*>(&A_lds[jt * 16 + l16][ks * 32 + q * 8]);
      acc = __builtin_amdgcn_mfma_f32_16x16x32_bf16(wf, a, acc, 0, 0, 0);
    }
    // D: col=slot(l16), row=e(q*4+j) -> 16B store
    *reinterpret_cast<f32x4*>(&emb48[jt * 16 + l16][e0 + q * 4]) = acc;
  }
  WAIT_LGKM0; BARRIER();

  // ---- 4) conv: emb_c[tl][e] = cb + sum_j cw[e,j]*emb48[13+tl+j][e] (batch zero-pad) ----
#pragma unroll
  for (int it = 0; it < 4; ++it) {
    int ii = it * 256 + tid;
    int tl = ii >> 5, e = ii & 31;
    int s = (t0 & 4095) + tl;
    float a = cb[e];
#pragma unroll
    for (int j = 0; j < 4; ++j)
      if (s - 3 + j >= 0) a += cw[e * 4 + j] * emb48[13 + tl + j][e];
    emb_c[tl][e] = a;
  }
  WAIT_LGKM0; BARRIER();

  // ---- 5) gate MLP: wave (tt,ee) owns 16x16 tile, full K; vmem-clean loop ----
  const int tt = wid >> 1, ee = wid & 1;
  const int R = tt * 16 + l16;
  const unsigned sw = ((unsigned)R & 7u) << 4;
  const char* hb0 = (const char*)&hbuf[0][R][0];
  const char* hb1 = (const char*)&hbuf[1][R][0];
  const int Rb = ee * 16 + l16;
  const unsigned swb = ((unsigned)Rb & 7u) << 4;
  const char* wb0 = (const char*)&wgbuf[0][Rb][0];
  const char* wb1 = (const char*)&wgbuf[1][Rb][0];
  f32x4 acc = {0.f, 0.f, 0.f, 0.f};

  for (int kc = 0; kc < NCH - 1; ++kc) {
    WAIT_VM(4);   // chunk kc landed (S(kc+1)'s 4 instrs may still fly)
    BARRIER();
    const char* hb = (kc & 1) ? hb1 : hb0;
    const char* wb = (kc & 1) ? wb1 : wb0;
    unsigned x0 = q * 32u;
    float4 a0 = *reinterpret_cast<const float4*>(hb + (x0 ^ sw));
    float4 a1 = *reinterpret_cast<const float4*>(hb + ((x0 + 16) ^ sw));
    float4 a2 = *reinterpret_cast<const float4*>(hb + ((x0 + 128) ^ sw));
    float4 a3 = *reinterpret_cast<const float4*>(hb + ((x0 + 144) ^ sw));
    float4 b0 = *reinterpret_cast<const float4*>(wb + (x0 ^ swb));
    float4 b1 = *reinterpret_cast<const float4*>(wb + ((x0 + 16) ^ swb));
    float4 b2 = *reinterpret_cast<const float4*>(wb + ((x0 + 128) ^ swb));
    float4 b3 = *reinterpret_cast<const float4*>(wb + ((x0 + 144) ^ swb));
    short8 A0 = pack8(a0, a1), A1 = pack8(a2, a3);
    short8 B0 = pack8(b0, b1), B1 = pack8(b2, b3);
    WAIT_LGKM0;   // our ds_reads of chunk kc are in regs
    BARRIER();    // all waves done with buf[kc&1]
    if (kc < NCH - 2) STAGE(kc & 1, kc + 2);  // prefetch flies across barriers
    acc = __builtin_amdgcn_mfma_f32_16x16x32_bf16(A0, B0, acc, 0, 0, 0);
    acc = __builtin_amdgcn_mfma_f32_16x16x32_bf16(A1, B1, acc, 0, 0, 0);
  }
  {  // final chunk (NCH-1, odd -> buf1), full drain
    WAIT_VM(0);
    BARRIER();
    unsigned x0 = q * 32u;
    float4 a0 = *reinterpret_cast<const float4*>(hb1 + (x0 ^ sw));
    float4 a1 = *reinterpret_cast<const float4*>(hb1 + ((x0 + 16) ^ sw));
    float4 a2 = *reinterpret_cast<const float4*>(hb1 + ((x0 + 128) ^ sw));
    float4 a3 = *reinterpret_cast<const float4*>(hb1 + ((x0 + 144) ^ sw));
    float4 b0 = *reinterpret_cast<const float4*>(wb1 + (x0 ^ swb));
    float4 b1 = *reinterpret_cast<const float4*>(wb1 + ((x0 + 16) ^ swb));
    float4 b2 = *reinterpret_cast<const float4*>(wb1 + ((x0 + 128) ^ swb));
    float4 b3 = *reinterpret_cast<const float4*>(wb1 + ((x0 + 144) ^ swb));
    acc = __builtin_amdgcn_mfma_f32_16x16x32_bf16(pack8(a0, a1), pack8(b0, b1), acc, 0, 0, 0);
    acc = __builtin_amdgcn_mfma_f32_16x16x32_bf16(pack8(a2, a3), pack8(b2, b3), acc, 0, 0, 0);
  }

  // ---- 6) sigmoid * conv-emb -> ge_lds (each wave writes its own 16x16 quadrant) ----
#pragma unroll
  for (int j = 0; j < 4; ++j) {
    int r = tt * 16 + q * 4 + j, c = ee * 16 + l16;
    float g = 1.f / (1.f + __expf(-acc[j]));
    ge_lds[r][c] = f2bf(g * emb_c[r][c]);
  }
  WAIT_LGKM0; BARRIER();

  // ---- 7) out[t,h] = ge @ Wo.T (swapped -> float4 stores); 512 h-cols/wave ----
  short8 Af0 = *reinterpret_cast<const short8*>(&ge_lds[l16][q * 8]);
  short8 Af1 = *reinterpret_cast<const short8*>(&ge_lds[16 + l16][q * 8]);
  float* orow0 = out + (size_t)(t0 + l16) * HSZ;
  float* orow1 = out + (size_t)(t0 + 16 + l16) * HSZ;
  int hbase = wid * 512;
  for (int ht = 0; ht < 32; ++ht) {
    int h0 = hbase + ht * 16;
    short8 aw = load8_bf(Wo + (size_t)(h0 + l16) * 32 + q * 8);
    f32x4 z = {0.f, 0.f, 0.f, 0.f};
    f32x4 o0 = __builtin_amdgcn_mfma_f32_16x16x32_bf16(aw, Af0, z, 0, 0, 0);
    f32x4 o1 = __builtin_amdgcn_mfma_f32_16x16x32_bf16(aw, Af1, z, 0, 0, 0);
    *reinterpret_cast<f32x4*>(orow0 + h0 + q * 4) = o0;
    *reinterpret_cast<f32x4*>(orow1 + h0 + q * 4) = o1;
  }
}

extern "C" void kernel_launch(void* const* d_in, const int* in_sizes, int n_in,
                              void* d_out, int out_size, void* d_ws, size_t ws_size,
                              hipStream_t stream) {
  const int* ids = (const int*)d_in[0];
  const float* hidden = (const float*)d_in[1];
  const int* mapping = (const int*)d_in[2];
  const unsigned* mult = (const unsigned*)d_in[3];  // delivered as int32; low bits exact
  const float* table = (const float*)d_in[4];
  const float* cw = (const float*)d_in[5];
  const float* cb = (const float*)d_in[6];
  const float* Wh = (const float*)d_in[7];
  const float* Wg = (const float*)d_in[8];
  const float* Wo = (const float*)d_in[9];
  float* out = (float*)d_out;

  engram_fused<<<512, 256, 0, stream>>>(ids, mapping, mult, table, Wh, hidden,
                                        cw, cb, Wg, Wo, out);
}